// Round 4
// baseline (176.375 us; speedup 1.0000x reference)
//
#include <hip/hip_runtime.h>
#include <hip/hip_bf16.h>

typedef __hip_bfloat16 bf16;
typedef __attribute__((ext_vector_type(8))) short  bfrag;   // 8 bf16 (4 VGPR) MFMA A/B frag
typedef __attribute__((ext_vector_type(4))) float  facc;    // MFMA C/D frag
typedef __attribute__((ext_vector_type(4))) short  short4v; // 4 bf16 = 8B packed store

#define B_   8
#define T_   1024
#define C_   768
#define H_   12
#define HD_  64
#define M_   (B_ * T_)   // 8192
#define N3_  (3 * C_)    // 2304

// Q is stored pre-scaled by 0.125*log2(e) so flash softmax is p = exp2(s - M2)
#define QSCALE_ 0.18033688011112042f
#define M2_     17.312340490667562f

__device__ __forceinline__ float fexp2(float x) { return __builtin_amdgcn_exp2f(x); }

__device__ __forceinline__ void gload_lds16(const bf16* g, bf16* l) {
    __builtin_amdgcn_global_load_lds((const __attribute__((address_space(1))) void*)g,
                                     (__attribute__((address_space(3))) void*)l, 16, 0, 0);
}
__device__ __forceinline__ short bfbits(float f) {
    bf16 b = __float2bfloat16(f);
    return *reinterpret_cast<short*>(&b);
}

// ---------- fused converts: x->bf16, W_attn->bf16^T, W_proj->bf16^T ----------
#define XBLK 6144                       // x: 6291456 / (256*4)
#define WABLK 1728                      // (2304/32)*(768/32)
__global__ __launch_bounds__(256) void cvt_all_kernel(
        const float* __restrict__ x,  bf16* __restrict__ xb,
        const float* __restrict__ wa, bf16* __restrict__ wat,
        const float* __restrict__ wp, bf16* __restrict__ wpt) {
    const int bid = blockIdx.x, t = threadIdx.x;
    if (bid < XBLK) {
        const size_t i = ((size_t)bid * 256 + t) * 4;
        const float4 v = *(const float4*)(x + i);
        bf16* o = xb + i;
        o[0] = __float2bfloat16(v.x); o[1] = __float2bfloat16(v.y);
        o[2] = __float2bfloat16(v.z); o[3] = __float2bfloat16(v.w);
        return;
    }
    __shared__ float tile[32][33];
    const float* w; bf16* wt; int N, tI;
    if (bid < XBLK + WABLK) { w = wa; wt = wat; N = N3_; tI = bid - XBLK; }
    else                    { w = wp; wt = wpt; N = C_;  tI = bid - XBLK - WABLK; }
    const int ntn = N / 32;
    const int n0 = (tI % ntn) * 32, k0 = (tI / ntn) * 32;
    const int tx = t & 31, ty = t >> 5;        // 32 x 8
    for (int i = ty; i < 32; i += 8) tile[i][tx] = w[(size_t)(k0 + i) * N + n0 + tx];
    __syncthreads();
    for (int i = ty; i < 32; i += 8)
        wt[(size_t)(n0 + i) * C_ + k0 + tx] = __float2bfloat16(tile[tx][i]);
}

// ---------- staggered double-buffered GEMM core: BM=128, BN=96, BK=64 ----------
// 256 threads = 4 waves (2 row x 2 col), wave tile 64x48, acc[4][3] (48 AGPR).
// LDS 56 KB dbuf -> 2 blocks/CU with margin (112 KB/CU). ONE sync per K-tile.
// K-OFFSET STAGGER: each block starts its K-loop at kt0 (= (id>>3)%12) and
// wraps mod 12. Co-resident blocks are out of phase, so one block's
// vmcnt-drain-at-sync overlaps the other's ds_read+MFMA phase (anti-convoy).
// Accumulation-order change only; f32 reorder error ~1e-5 << bf16 rounding.

template<bool SWAPPED>
__device__ __forceinline__ void gemm96_core(
        const bf16* __restrict__ Ap, const bf16* __restrict__ Bp,
        const int m0, const int n0, const int kt0,
        bf16* smem, facc (&acc)[4][3]) {
    constexpr int KD = 768, NT = 12;
    bf16* As = smem;                  // [2][128*64] = 32 KB
    bf16* Bs = smem + 2 * 8192;       // [2][96*64]  = 24 KB
    const int t = threadIdx.x, w = t >> 6, lane = t & 63;
    const int wrow = (w >> 1) * 64;                  // 2 row-waves
    const int wcol = (w & 1) * 48;                   // 2 col-waves
    const int fr = lane & 15, quad = lane >> 4;
    const int pc0 = (quad ^ (fr & 7)) * 8;           // swizzled read chunk, kk=0
    const int pc1 = ((quad + 4) ^ (fr & 7)) * 8;     // kk=1
    const int srow = t >> 3;                         // 0..31 staging row
    const int schunk = ((t & 7) ^ (srow & 7)) * 8;   // swizzled source chunk
    const int sdo = t * 8;                           // linear LDS dest

    const bf16* Ag = Ap + (size_t)(m0 + srow) * KD + schunk;
    const bf16* Bg = Bp + (size_t)(n0 + srow) * KD + schunk;

#pragma unroll
    for (int i = 0; i < 4; ++i)
#pragma unroll
        for (int c = 0; c < 3; ++c)
#pragma unroll
            for (int r = 0; r < 4; ++r) acc[i][c][r] = 0.f;

    auto stageA = [&](bf16* dst, int k0) {           // 4 passes of 32 rows
        const bf16* s = Ag + k0;
        bf16* d = dst + sdo;
#pragma unroll
        for (int r = 0; r < 4; ++r)
            gload_lds16(s + (size_t)(r * 32) * KD, d + r * 2048);
    };
    auto stageB = [&](bf16* dst, int k0) {           // 3 passes of 32 rows
        const bf16* s = Bg + k0;
        bf16* d = dst + sdo;
#pragma unroll
        for (int r = 0; r < 3; ++r)
            gload_lds16(s + (size_t)(r * 32) * KD, d + r * 2048);
    };

    // prologue: stage tile kt0
    stageA(As, kt0 * 64);
    stageB(Bs, kt0 * 64);
    __syncthreads();

    int kt = kt0;
#pragma unroll 2
    for (int s = 0; s < NT; ++s) {
        const int cb = s & 1;
        const bf16* AsC = As + cb * 8192;
        const bf16* BsC = Bs + cb * 6144;
        const int ktn = (kt + 1 == NT) ? 0 : kt + 1;
        // issue next-tile staging FIRST so gloads overlap this tile's compute
        if (s + 1 < NT) {
            stageA(As + (cb ^ 1) * 8192, ktn * 64);
            stageB(Bs + (cb ^ 1) * 6144, ktn * 64);
        }
        bfrag af[4][2];
#pragma unroll
        for (int i = 0; i < 4; ++i) {
            const bf16* ar = AsC + (wrow + i * 16 + fr) * 64;
            af[i][0] = *(const bfrag*)(ar + pc0);
            af[i][1] = *(const bfrag*)(ar + pc1);
        }
#pragma unroll
        for (int c = 0; c < 3; ++c) {
            const bf16* br = BsC + (wcol + c * 16 + fr) * 64;
            bfrag b0 = *(const bfrag*)(br + pc0);
            bfrag b1 = *(const bfrag*)(br + pc1);
#pragma unroll
            for (int i = 0; i < 4; ++i) {
                if constexpr (SWAPPED) {
                    acc[i][c] = __builtin_amdgcn_mfma_f32_16x16x32_bf16(b0, af[i][0], acc[i][c], 0, 0, 0);
                    acc[i][c] = __builtin_amdgcn_mfma_f32_16x16x32_bf16(b1, af[i][1], acc[i][c], 0, 0, 0);
                } else {
                    acc[i][c] = __builtin_amdgcn_mfma_f32_16x16x32_bf16(af[i][0], b0, acc[i][c], 0, 0, 0);
                    acc[i][c] = __builtin_amdgcn_mfma_f32_16x16x32_bf16(af[i][1], b1, acc[i][c], 0, 0, 0);
                }
            }
        }
        __syncthreads();   // drains vmcnt+lgkm; buffer flip
        kt = ktn;
    }
}

// qkv: A=xb [8192x768], Bt=WaT [2304x768] -> Q,K [B,H,T,64] bf16 (swapped, packed),
// V transposed Vt [B,H,64,T] (non-swapped). Grid 1536 = 3 clean rounds of 2/CU.
__global__ __launch_bounds__(256, 2) void qkv_s_kernel(
        const bf16* __restrict__ xb, const bf16* __restrict__ wat,
        const float* __restrict__ bias,
        bf16* __restrict__ Q, bf16* __restrict__ K, bf16* __restrict__ Vt) {
    extern __shared__ bf16 smem[];
    const int id = blockIdx.x;
    const int wg = (id & 7) * 192 + (id >> 3);     // bijective XCD swizzle (1536%8==0)
    const int bx = wg % 24, by = wg / 24;
    const int m0 = by * 128, n0 = bx * 96;
    const int kt0 = (id >> 3) % 12;                // anti-convoy K-offset
    const int which = n0 / C_;                     // block-uniform: 0=Q 1=K 2=V

    facc acc[4][3];
    if (which < 2) gemm96_core<true >(xb, wat, m0, n0, kt0, smem, acc);
    else           gemm96_core<false>(xb, wat, m0, n0, kt0, smem, acc);

    const int t = threadIdx.x, w = t >> 6, lane = t & 63;
    const int wr = (w >> 1) * 64, wc = (w & 1) * 48;
    const int fr = lane & 15, quad = lane >> 4;
    const int bb = m0 >> 10;                       // uniform batch index
    if (which < 2) {
        bf16* dst = which ? K : Q;
        const float sc = which ? 1.0f : QSCALE_;
#pragma unroll
        for (int i = 0; i < 4; ++i) {
            const int tt = (m0 & 1023) + wr + i * 16 + fr;     // token (lane-major)
#pragma unroll
            for (int c = 0; c < 3; ++c) {
                const int colbase = n0 + wc + c * 16 + quad * 4;
                const int cc = colbase - which * C_;
                const int h = cc >> 6, d0 = cc & 63;
                const float4 bv = *(const float4*)(bias + colbase);
                short4v pk;
                pk[0] = bfbits((acc[i][c][0] + bv.x) * sc);
                pk[1] = bfbits((acc[i][c][1] + bv.y) * sc);
                pk[2] = bfbits((acc[i][c][2] + bv.z) * sc);
                pk[3] = bfbits((acc[i][c][3] + bv.w) * sc);
                *(short4v*)(dst + ((size_t)(bb * H_ + h) * T_ + tt) * HD_ + d0) = pk;
            }
        }
    } else {
#pragma unroll
        for (int i = 0; i < 4; ++i) {
            const int tt0 = (m0 & 1023) + wr + i * 16 + quad * 4;  // token, +r over pack
#pragma unroll
            for (int c = 0; c < 3; ++c) {
                const int col = n0 + wc + c * 16 + fr;
                const int cc = col - 2 * C_;
                const int h = cc >> 6, d = cc & 63;
                const float bv = bias[col];
                short4v pk;
                pk[0] = bfbits(acc[i][c][0] + bv);
                pk[1] = bfbits(acc[i][c][1] + bv);
                pk[2] = bfbits(acc[i][c][2] + bv);
                pk[3] = bfbits(acc[i][c][3] + bv);
                *(short4v*)(Vt + ((size_t)(bb * H_ + h) * HD_ + d) * T_ + tt0) = pk;
            }
        }
    }
}

// proj: A=Y [8192x768] bf16, Bt=WpT [768x768] -> fp32 out + bias (swapped).
// Grid 512 = 2 clean rounds of 2/CU (was 1 block/CU: zero cross-block overlap).
__global__ __launch_bounds__(256, 2) void proj_s_kernel(
        const bf16* __restrict__ y, const bf16* __restrict__ wpt,
        const float* __restrict__ bias, float* __restrict__ out) {
    extern __shared__ bf16 smem[];
    const int id = blockIdx.x;
    const int wg = (id & 7) * 64 + (id >> 3);      // bijective XCD swizzle (512%8==0)
    const int bx = wg % 8, by = wg / 8;
    const int m0 = by * 128, n0 = bx * 96;
    const int kt0 = (id >> 3) % 12;                // anti-convoy K-offset

    facc acc[4][3];
    gemm96_core<true>(y, wpt, m0, n0, kt0, smem, acc);

    const int t = threadIdx.x, w = t >> 6, lane = t & 63;
    const int wr = (w >> 1) * 64, wc = (w & 1) * 48;
    const int fr = lane & 15, quad = lane >> 4;
#pragma unroll
    for (int i = 0; i < 4; ++i) {
        const int row = m0 + wr + i * 16 + fr;
#pragma unroll
        for (int c = 0; c < 3; ++c) {
            const int colbase = n0 + wc + c * 16 + quad * 4;
            const float4 bv = *(const float4*)(bias + colbase);
            float4 v;
            v.x = acc[i][c][0] + bv.x;
            v.y = acc[i][c][1] + bv.y;
            v.z = acc[i][c][2] + bv.z;
            v.w = acc[i][c][3] + bv.w;
            *(float4*)(out + (size_t)row * C_ + colbase) = v;
        }
    }
}

// ---------- flash attention: exp2 static-max softmax + 2 K-tiles per barrier ----------
__global__ __launch_bounds__(256) void flash_attn_kernel(
        const bf16* __restrict__ Q, const bf16* __restrict__ K,
        const bf16* __restrict__ Vt, bf16* __restrict__ Y) {
    const int id   = blockIdx.x;
    const int bh   = (id & 7) * 12 + ((id >> 3) % 12);    // XCD affinity
    const int qpair = (id >> 3) / 12;                     // 0..7
    const int t = threadIdx.x, w = t >> 6, lane = t & 63;
    const int fr = lane & 15, quad = lane >> 4, fq = quad * 8;

    __shared__ bf16 sK[2][64 * 64];       // [buf][key][dim], chunk-swizzled
    __shared__ bf16 sVt[2][64 * 64];      // [buf][dim][key], chunk-swizzled
    __shared__ bf16 sP[4][16][72];        // wave-private P, row stride 72 (16B aligned)

    const bf16* Kbh = K  + (size_t)bh * T_ * HD_;
    const bf16* Vbh = Vt + (size_t)bh * HD_ * T_;
    const int b_ = bh / H_, h_ = bh % H_;

    const int srow = t >> 3;                                // 0..31 (staging row)
    const int sgc  = ((t & 7) ^ (srow & 7)) * 8;            // swizzled source chunk
    const int c0   = (quad ^ (fr & 7)) * 8;                 // swizzled read chunk

    for (int phase = 0; phase < 2; ++phase) {
        const int qt = (phase == 0) ? (15 - qpair) : qpair; // heavy tile first
        const int q0 = qt * 64;

        const bf16* qbase = Q + ((size_t)bh * T_ + q0 + w * 16 + fr) * HD_;
        bfrag qa0 = *(const bfrag*)(qbase + fq);
        bfrag qa1 = *(const bfrag*)(qbase + 32 + fq);

        facc o[4];
        for (int nb = 0; nb < 4; ++nb) for (int r = 0; r < 4; ++r) o[nb][r] = 0.f;
        float rowl[4] = {0.f, 0.f, 0.f, 0.f};

        auto tile_step = [&](int kt, const bf16* sKp, const bf16* sVp) {
            const int k0 = kt * 64;
            facc s[4];
            for (int nb = 0; nb < 4; ++nb) for (int r = 0; r < 4; ++r) s[nb][r] = 0.f;
            __builtin_amdgcn_s_setprio(1);                     // T5: favor MFMA wave
            for (int nb = 0; nb < 4; ++nb) {
                const bf16* kr = sKp + (nb * 16 + fr) * 64;
                bfrag kb0 = *(const bfrag*)(kr + c0);
                bfrag kb1 = *(const bfrag*)(kr + (c0 ^ 32));
                s[nb] = __builtin_amdgcn_mfma_f32_16x16x32_bf16(qa0, kb0, s[nb], 0, 0, 0);
                s[nb] = __builtin_amdgcn_mfma_f32_16x16x32_bf16(qa1, kb1, s[nb], 0, 0, 0);
            }
            __builtin_amdgcn_s_setprio(0);
            const int mrow0 = q0 + w * 16 + quad * 4;   // + r
            float p[4][4];
            if (kt == qt) {
                for (int nb = 0; nb < 4; ++nb) {
                    const int n_g = k0 + nb * 16 + fr;
                    for (int r = 0; r < 4; ++r) {
                        const float a = (n_g > mrow0 + r) ? -1e30f : s[nb][r] - M2_;
                        p[nb][r] = fexp2(a);
                    }
                }
            } else {
                for (int nb = 0; nb < 4; ++nb)
                    for (int r = 0; r < 4; ++r)
                        p[nb][r] = fexp2(s[nb][r] - M2_);
            }
            for (int r = 0; r < 4; ++r)
                rowl[r] += p[0][r] + p[1][r] + p[2][r] + p[3][r];
            for (int nb = 0; nb < 4; ++nb)
                for (int r = 0; r < 4; ++r)
                    sP[w][quad * 4 + r][nb * 16 + fr] = __float2bfloat16(p[nb][r]);
            bfrag pa0 = *(const bfrag*)(&sP[w][fr][fq]);
            bfrag pa1 = *(const bfrag*)(&sP[w][fr][32 + fq]);
            __builtin_amdgcn_s_setprio(1);                     // T5: favor MFMA wave
            for (int nb = 0; nb < 4; ++nb) {
                const bf16* vr = sVp + (nb * 16 + fr) * 64;
                bfrag vb0 = *(const bfrag*)(vr + c0);
                bfrag vb1 = *(const bfrag*)(vr + (c0 ^ 32));
                o[nb] = __builtin_amdgcn_mfma_f32_16x16x32_bf16(pa0, vb0, o[nb], 0, 0, 0);
                o[nb] = __builtin_amdgcn_mfma_f32_16x16x32_bf16(pa1, vb1, o[nb], 0, 0, 0);
            }
            __builtin_amdgcn_s_setprio(0);
        };

        for (int kt = 0; kt <= qt; kt += 2) {
            const int k0 = kt * 64;
            const bool two = (kt + 1 <= qt);
            gload_lds16(Kbh + (size_t)(k0 + srow) * HD_ + sgc,      sK[0] + t * 8);
            gload_lds16(Kbh + (size_t)(k0 + 32 + srow) * HD_ + sgc, sK[0] + 2048 + t * 8);
            gload_lds16(Vbh + (size_t)srow * T_ + k0 + sgc,         sVt[0] + t * 8);
            gload_lds16(Vbh + (size_t)(srow + 32) * T_ + k0 + sgc,  sVt[0] + 2048 + t * 8);
            if (two) {
                const int k1 = k0 + 64;
                gload_lds16(Kbh + (size_t)(k1 + srow) * HD_ + sgc,      sK[1] + t * 8);
                gload_lds16(Kbh + (size_t)(k1 + 32 + srow) * HD_ + sgc, sK[1] + 2048 + t * 8);
                gload_lds16(Vbh + (size_t)srow * T_ + k1 + sgc,         sVt[1] + t * 8);
                gload_lds16(Vbh + (size_t)(srow + 32) * T_ + k1 + sgc,  sVt[1] + 2048 + t * 8);
            }
            __syncthreads();
            tile_step(kt, sK[0], sVt[0]);
            if (two) tile_step(kt + 1, sK[1], sVt[1]);
            __syncthreads();
        }

        for (int r = 0; r < 4; ++r) {
            float l = rowl[r];
            l += __shfl_xor(l, 1);
            l += __shfl_xor(l, 2);
            l += __shfl_xor(l, 4);
            l += __shfl_xor(l, 8);
            const float inv = 1.0f / l;
            const int tt = q0 + w * 16 + quad * 4 + r;
            bf16* yrow = Y + ((size_t)b_ * T_ + tt) * C_ + h_ * HD_;
            for (int nb = 0; nb < 4; ++nb)
                yrow[nb * 16 + fr] = __float2bfloat16(o[nb][r] * inv);
        }
    }
}

extern "C" void kernel_launch(void* const* d_in, const int* in_sizes, int n_in,
                              void* d_out, int out_size, void* d_ws, size_t ws_size,
                              hipStream_t stream) {
    const float* x      = (const float*)d_in[0];
    const float* W_attn = (const float*)d_in[1];
    const float* b_attn = (const float*)d_in[2];
    const float* W_proj = (const float*)d_in[3];
    const float* b_proj = (const float*)d_in[4];
    float* out = (float*)d_out;

    const size_t per = (size_t)B_ * H_ * T_ * HD_;   // 6291456 bf16
    bf16* Q   = (bf16*)d_ws;
    bf16* K   = Q + per;
    bf16* Vt  = K + per;                 // transposed V [B,H,64,T]
    bf16* XbY = Vt + per;                // x-bf16, later attention output Y
    bf16* WaT = XbY + per;
    bf16* WpT = WaT + (size_t)N3_ * C_;

    static bool s_attr = false;
    if (!s_attr) {
        hipFuncSetAttribute((const void*)qkv_s_kernel,
                            hipFuncAttributeMaxDynamicSharedMemorySize, 57344);
        hipFuncSetAttribute((const void*)proj_s_kernel,
                            hipFuncAttributeMaxDynamicSharedMemorySize, 57344);
        s_attr = true;
    }

    cvt_all_kernel<<<dim3(XBLK + WABLK + 576), dim3(256), 0, stream>>>(
        x, XbY, W_attn, WaT, W_proj, WpT);
    qkv_s_kernel<<<dim3(1536), dim3(256), 57344, stream>>>(
        XbY, WaT, b_attn, Q, K, Vt);
    flash_attn_kernel<<<dim3(768), dim3(256), 0, stream>>>(Q, K, Vt, XbY);
    proj_s_kernel<<<dim3(512), dim3(256), 57344, stream>>>(
        XbY, WpT, b_proj, out);
}

// Round 5
// 171.373 us; speedup vs baseline: 1.0292x; 1.0292x over previous
//
#include <hip/hip_runtime.h>
#include <hip/hip_bf16.h>

typedef __hip_bfloat16 bf16;
typedef __attribute__((ext_vector_type(8))) short  bfrag;   // 8 bf16 (4 VGPR) MFMA A/B frag
typedef __attribute__((ext_vector_type(4))) float  facc;    // MFMA C/D frag
typedef __attribute__((ext_vector_type(4))) short  short4v; // 4 bf16 = 8B packed store

#define B_   8
#define T_   1024
#define C_   768
#define H_   12
#define HD_  64
#define M_   (B_ * T_)   // 8192
#define N3_  (3 * C_)    // 2304

// Q is stored pre-scaled by 0.125*log2(e) so flash softmax is p = exp2(s - M2)
#define QSCALE_ 0.18033688011112042f
#define M2_     17.312340490667562f

__device__ __forceinline__ float fexp2(float x) { return __builtin_amdgcn_exp2f(x); }

__device__ __forceinline__ void gload_lds16(const bf16* g, bf16* l) {
    __builtin_amdgcn_global_load_lds((const __attribute__((address_space(1))) void*)g,
                                     (__attribute__((address_space(3))) void*)l, 16, 0, 0);
}
__device__ __forceinline__ short bfbits(float f) {
    bf16 b = __float2bfloat16(f);
    return *reinterpret_cast<short*>(&b);
}

// ---------- fused converts: x->bf16, W_attn->bf16^T, W_proj->bf16^T ----------
#define XBLK 6144                       // x: 6291456 / (256*4)
#define WABLK 1728                      // (2304/32)*(768/32)
__global__ __launch_bounds__(256) void cvt_all_kernel(
        const float* __restrict__ x,  bf16* __restrict__ xb,
        const float* __restrict__ wa, bf16* __restrict__ wat,
        const float* __restrict__ wp, bf16* __restrict__ wpt) {
    const int bid = blockIdx.x, t = threadIdx.x;
    if (bid < XBLK) {
        const size_t i = ((size_t)bid * 256 + t) * 4;
        const float4 v = *(const float4*)(x + i);
        bf16* o = xb + i;
        o[0] = __float2bfloat16(v.x); o[1] = __float2bfloat16(v.y);
        o[2] = __float2bfloat16(v.z); o[3] = __float2bfloat16(v.w);
        return;
    }
    __shared__ float tile[32][33];
    const float* w; bf16* wt; int N, tI;
    if (bid < XBLK + WABLK) { w = wa; wt = wat; N = N3_; tI = bid - XBLK; }
    else                    { w = wp; wt = wpt; N = C_;  tI = bid - XBLK - WABLK; }
    const int ntn = N / 32;
    const int n0 = (tI % ntn) * 32, k0 = (tI / ntn) * 32;
    const int tx = t & 31, ty = t >> 5;        // 32 x 8
    for (int i = ty; i < 32; i += 8) tile[i][tx] = w[(size_t)(k0 + i) * N + n0 + tx];
    __syncthreads();
    for (int i = ty; i < 32; i += 8)
        wt[(size_t)(n0 + i) * C_ + k0 + tx] = __float2bfloat16(tile[tx][i]);
}

// ---------- counted-vmcnt double-buffered GEMM core: BM=128, BN=BNv ----------
// 256 threads = 4 waves (2 row x 2 col). LDS dbuf; 2 blocks/CU.
// THE FIX vs r3/r4: no __syncthreads in the K-loop. Per tile:
//   issue stage(t+1) [LD loads] -> s_waitcnt vmcnt(LD)  (= stage(t) done,
//   stage(t+1)'s LD loads stay IN FLIGHT across the whole compute) ->
//   s_barrier -> ds_read+MFMA (compiler lgkmcnt) -> s_barrier.
// The trailing barrier (no vmcnt drain!) only orders buffer reuse.
// vmcnt is per-wave; every wave issues exactly LD loads/tile, so the
// counted wait is uniform. sched_barrier(0) fences both barrier edges
// so the compiler can't move ds_reads across them (rule #18).

#define WAIT_VM(N) asm volatile("s_waitcnt vmcnt(" #N ")" ::: "memory")

template<int NB, bool SWAPPED>   // NB = BN/16 per block col count (12 or 6)
__device__ __forceinline__ void gemm_cv_core(
        const bf16* __restrict__ Ap, const bf16* __restrict__ Bp,
        const int m0, const int n0, const int kt0,
        bf16* smem, facc (&acc)[4][NB / 2]) {
    constexpr int KD = 768, NT = 12;
    constexpr int BN  = NB * 16;          // 192 or 96
    constexpr int NC  = NB / 2;           // per-wave col frags (6 or 3)
    constexpr int BSZ = BN * 64;          // elems per B buffer
    constexpr int LB  = BN / 32;          // B gload passes (6 or 3)
    constexpr int LD  = 4 + LB;           // loads per thread per tile (10 or 7)
    bf16* As = smem;                      // [2][128*64]
    bf16* Bs = smem + 2 * 8192;           // [2][BSZ]
    const int t = threadIdx.x, w = t >> 6, lane = t & 63;
    const int wrow = (w >> 1) * 64;                  // 2 row-waves
    const int wcol = (w & 1) * (NC * 16);            // 2 col-waves
    const int fr = lane & 15, quad = lane >> 4;
    const int pc0 = (quad ^ (fr & 7)) * 8;           // swizzled read chunk, kk=0
    const int pc1 = ((quad + 4) ^ (fr & 7)) * 8;     // kk=1
    const int srow = t >> 3;                         // 0..31 staging row
    const int schunk = ((t & 7) ^ (srow & 7)) * 8;   // swizzled source chunk
    const int sdo = t * 8;                           // linear LDS dest

    const bf16* Ag = Ap + (size_t)(m0 + srow) * KD + schunk;
    const bf16* Bg = Bp + (size_t)(n0 + srow) * KD + schunk;

#pragma unroll
    for (int i = 0; i < 4; ++i)
#pragma unroll
        for (int c = 0; c < NC; ++c)
#pragma unroll
            for (int r = 0; r < 4; ++r) acc[i][c][r] = 0.f;

    auto stageA = [&](bf16* dst, int k0) {           // 4 passes of 32 rows
        const bf16* s = Ag + k0;
        bf16* d = dst + sdo;
#pragma unroll
        for (int r = 0; r < 4; ++r)
            gload_lds16(s + (size_t)(r * 32) * KD, d + r * 2048);
    };
    auto stageB = [&](bf16* dst, int k0) {           // LB passes of 32 rows
        const bf16* s = Bg + k0;
        bf16* d = dst + sdo;
#pragma unroll
        for (int r = 0; r < LB; ++r)
            gload_lds16(s + (size_t)(r * 32) * KD, d + r * 2048);
    };

    // prologue: stage tile kt0 into buffer 0
    stageA(As, kt0 * 64);
    stageB(Bs, kt0 * 64);

    int kt = kt0;
#pragma unroll 2
    for (int s = 0; s < NT; ++s) {
        const int cb = s & 1;
        const bf16* AsC = As + cb * 8192;
        const bf16* BsC = Bs + cb * BSZ;
        const int ktn = (kt + 1 == NT) ? 0 : kt + 1;
        if (s + 1 < NT) {
            stageA(As + (cb ^ 1) * 8192, ktn * 64);
            stageB(Bs + (cb ^ 1) * BSZ,  ktn * 64);
            if constexpr (LD == 10) WAIT_VM(10); else WAIT_VM(7);
        } else {
            WAIT_VM(0);
        }
        __builtin_amdgcn_s_barrier();        // stage(t) visible to all waves
        __builtin_amdgcn_sched_barrier(0);
        __builtin_amdgcn_s_setprio(1);
        bfrag af[4][2];
#pragma unroll
        for (int i = 0; i < 4; ++i) {
            const bf16* ar = AsC + (wrow + i * 16 + fr) * 64;
            af[i][0] = *(const bfrag*)(ar + pc0);
            af[i][1] = *(const bfrag*)(ar + pc1);
        }
#pragma unroll
        for (int c = 0; c < NC; ++c) {
            const bf16* br = BsC + (wcol + c * 16 + fr) * 64;
            bfrag b0 = *(const bfrag*)(br + pc0);
            bfrag b1 = *(const bfrag*)(br + pc1);
#pragma unroll
            for (int i = 0; i < 4; ++i) {
                if constexpr (SWAPPED) {
                    acc[i][c] = __builtin_amdgcn_mfma_f32_16x16x32_bf16(b0, af[i][0], acc[i][c], 0, 0, 0);
                    acc[i][c] = __builtin_amdgcn_mfma_f32_16x16x32_bf16(b1, af[i][1], acc[i][c], 0, 0, 0);
                } else {
                    acc[i][c] = __builtin_amdgcn_mfma_f32_16x16x32_bf16(af[i][0], b0, acc[i][c], 0, 0, 0);
                    acc[i][c] = __builtin_amdgcn_mfma_f32_16x16x32_bf16(af[i][1], b1, acc[i][c], 0, 0, 0);
                }
            }
        }
        __builtin_amdgcn_s_setprio(0);
        __builtin_amdgcn_sched_barrier(0);
        __builtin_amdgcn_s_barrier();        // all reads of this buffer done
        kt = ktn;
    }
}

// qkv: A=xb [8192x768], Bt=WaT [2304x768] -> Q,K [B,H,T,64] bf16 (swapped, packed),
// V transposed Vt [B,H,64,T] (non-swapped). Grid 768 = 64 rows x 12 cols.
// XCD map: xcd owns 16 rows x 6 cols; col-major walk inside the chunk so
// co-resident blocks share one W col-panel (295 KB) + 2 x-panels (~0.7 MB
// working set << 4 MB per-XCD L2) instead of thrashing full WaT.
__global__ __launch_bounds__(256, 2) void qkv_p_kernel(
        const bf16* __restrict__ xb, const bf16* __restrict__ wat,
        const float* __restrict__ bias,
        bf16* __restrict__ Q, bf16* __restrict__ K, bf16* __restrict__ Vt) {
    extern __shared__ bf16 smem[];
    const int id = blockIdx.x;
    const int xcd = id & 7, L = id >> 3;           // L in 0..95
    const int rgrp = xcd >> 1, cgrp = xcd & 1;     // 4 row-groups x 2 col-groups
    const int r_l = L & 15, c_l = L >> 4;          // 16 rows x 6 cols, col-major
    const int by = rgrp * 16 + r_l, bx = cgrp * 6 + c_l;
    const int m0 = by * 128, n0 = bx * 192;
    const int kt0 = L % 12;                        // anti-convoy K-offset
    const int which = bx / 4;                      // block-uniform: 0=Q 1=K 2=V

    facc acc[4][6];
    if (which < 2) gemm_cv_core<12, true >(xb, wat, m0, n0, kt0, smem, acc);
    else           gemm_cv_core<12, false>(xb, wat, m0, n0, kt0, smem, acc);

    const int t = threadIdx.x, w = t >> 6, lane = t & 63;
    const int wr = (w >> 1) * 64, wc = (w & 1) * 96;
    const int fr = lane & 15, quad = lane >> 4;
    const int bb = m0 >> 10;                       // uniform batch index
    if (which < 2) {
        bf16* dst = which ? K : Q;
        const float sc = which ? 1.0f : QSCALE_;
#pragma unroll
        for (int i = 0; i < 4; ++i) {
            const int tt = (m0 & 1023) + wr + i * 16 + fr;     // token (lane-major)
#pragma unroll
            for (int c = 0; c < 6; ++c) {
                const int colbase = n0 + wc + c * 16 + quad * 4;
                const int cc = colbase - which * C_;
                const int h = cc >> 6, d0 = cc & 63;
                const float4 bv = *(const float4*)(bias + colbase);
                short4v pk;
                pk[0] = bfbits((acc[i][c][0] + bv.x) * sc);
                pk[1] = bfbits((acc[i][c][1] + bv.y) * sc);
                pk[2] = bfbits((acc[i][c][2] + bv.z) * sc);
                pk[3] = bfbits((acc[i][c][3] + bv.w) * sc);
                *(short4v*)(dst + ((size_t)(bb * H_ + h) * T_ + tt) * HD_ + d0) = pk;
            }
        }
    } else {
#pragma unroll
        for (int i = 0; i < 4; ++i) {
            const int tt0 = (m0 & 1023) + wr + i * 16 + quad * 4;  // token, +r over pack
#pragma unroll
            for (int c = 0; c < 6; ++c) {
                const int col = n0 + wc + c * 16 + fr;
                const int cc = col - 2 * C_;
                const int h = cc >> 6, d = cc & 63;
                const float bv = bias[col];
                short4v pk;
                pk[0] = bfbits(acc[i][c][0] + bv);
                pk[1] = bfbits(acc[i][c][1] + bv);
                pk[2] = bfbits(acc[i][c][2] + bv);
                pk[3] = bfbits(acc[i][c][3] + bv);
                *(short4v*)(Vt + ((size_t)(bb * H_ + h) * HD_ + d) * T_ + tt0) = pk;
            }
        }
    }
}

// proj: A=Y [8192x768] bf16, Bt=WpT [768x768] -> fp32 out + bias (swapped).
// Grid 512 = 64 rows x 8 cols = ONE clean round of 2/CU.
__global__ __launch_bounds__(256, 2) void proj_p_kernel(
        const bf16* __restrict__ y, const bf16* __restrict__ wpt,
        const float* __restrict__ bias, float* __restrict__ out) {
    extern __shared__ bf16 smem[];
    const int id = blockIdx.x;
    const int xcd = id & 7, L = id >> 3;           // L in 0..63
    const int rgrp = xcd >> 1, cgrp = xcd & 1;     // 4 row-groups x 2 col-groups
    const int r_l = L & 15, c_l = L >> 4;          // 16 rows x 4 cols, col-major
    const int by = rgrp * 16 + r_l, bx = cgrp * 4 + c_l;
    const int m0 = by * 128, n0 = bx * 96;
    const int kt0 = L % 12;                        // anti-convoy K-offset

    facc acc[4][3];
    gemm_cv_core<6, true>(y, wpt, m0, n0, kt0, smem, acc);

    const int t = threadIdx.x, w = t >> 6, lane = t & 63;
    const int wr = (w >> 1) * 64, wc = (w & 1) * 48;
    const int fr = lane & 15, quad = lane >> 4;
#pragma unroll
    for (int i = 0; i < 4; ++i) {
        const int row = m0 + wr + i * 16 + fr;
#pragma unroll
        for (int c = 0; c < 3; ++c) {
            const int colbase = n0 + wc + c * 16 + quad * 4;
            const float4 bv = *(const float4*)(bias + colbase);
            float4 v;
            v.x = acc[i][c][0] + bv.x;
            v.y = acc[i][c][1] + bv.y;
            v.z = acc[i][c][2] + bv.z;
            v.w = acc[i][c][3] + bv.w;
            *(float4*)(out + (size_t)row * C_ + colbase) = v;
        }
    }
}

// ---------- flash attention: exp2 static-max softmax + 2 K-tiles per barrier ----------
__global__ __launch_bounds__(256) void flash_attn_kernel(
        const bf16* __restrict__ Q, const bf16* __restrict__ K,
        const bf16* __restrict__ Vt, bf16* __restrict__ Y) {
    const int id   = blockIdx.x;
    const int bh   = (id & 7) * 12 + ((id >> 3) % 12);    // XCD affinity
    const int qpair = (id >> 3) / 12;                     // 0..7
    const int t = threadIdx.x, w = t >> 6, lane = t & 63;
    const int fr = lane & 15, quad = lane >> 4, fq = quad * 8;

    __shared__ bf16 sK[2][64 * 64];       // [buf][key][dim], chunk-swizzled
    __shared__ bf16 sVt[2][64 * 64];      // [buf][dim][key], chunk-swizzled
    __shared__ bf16 sP[4][16][72];        // wave-private P, row stride 72 (16B aligned)

    const bf16* Kbh = K  + (size_t)bh * T_ * HD_;
    const bf16* Vbh = Vt + (size_t)bh * HD_ * T_;
    const int b_ = bh / H_, h_ = bh % H_;

    const int srow = t >> 3;                                // 0..31 (staging row)
    const int sgc  = ((t & 7) ^ (srow & 7)) * 8;            // swizzled source chunk
    const int c0   = (quad ^ (fr & 7)) * 8;                 // swizzled read chunk

    for (int phase = 0; phase < 2; ++phase) {
        const int qt = (phase == 0) ? (15 - qpair) : qpair; // heavy tile first
        const int q0 = qt * 64;

        const bf16* qbase = Q + ((size_t)bh * T_ + q0 + w * 16 + fr) * HD_;
        bfrag qa0 = *(const bfrag*)(qbase + fq);
        bfrag qa1 = *(const bfrag*)(qbase + 32 + fq);

        facc o[4];
        for (int nb = 0; nb < 4; ++nb) for (int r = 0; r < 4; ++r) o[nb][r] = 0.f;
        float rowl[4] = {0.f, 0.f, 0.f, 0.f};

        auto tile_step = [&](int kt, const bf16* sKp, const bf16* sVp) {
            const int k0 = kt * 64;
            facc s[4];
            for (int nb = 0; nb < 4; ++nb) for (int r = 0; r < 4; ++r) s[nb][r] = 0.f;
            __builtin_amdgcn_s_setprio(1);                     // T5: favor MFMA wave
            for (int nb = 0; nb < 4; ++nb) {
                const bf16* kr = sKp + (nb * 16 + fr) * 64;
                bfrag kb0 = *(const bfrag*)(kr + c0);
                bfrag kb1 = *(const bfrag*)(kr + (c0 ^ 32));
                s[nb] = __builtin_amdgcn_mfma_f32_16x16x32_bf16(qa0, kb0, s[nb], 0, 0, 0);
                s[nb] = __builtin_amdgcn_mfma_f32_16x16x32_bf16(qa1, kb1, s[nb], 0, 0, 0);
            }
            __builtin_amdgcn_s_setprio(0);
            const int mrow0 = q0 + w * 16 + quad * 4;   // + r
            float p[4][4];
            if (kt == qt) {
                for (int nb = 0; nb < 4; ++nb) {
                    const int n_g = k0 + nb * 16 + fr;
                    for (int r = 0; r < 4; ++r) {
                        const float a = (n_g > mrow0 + r) ? -1e30f : s[nb][r] - M2_;
                        p[nb][r] = fexp2(a);
                    }
                }
            } else {
                for (int nb = 0; nb < 4; ++nb)
                    for (int r = 0; r < 4; ++r)
                        p[nb][r] = fexp2(s[nb][r] - M2_);
            }
            for (int r = 0; r < 4; ++r)
                rowl[r] += p[0][r] + p[1][r] + p[2][r] + p[3][r];
            for (int nb = 0; nb < 4; ++nb)
                for (int r = 0; r < 4; ++r)
                    sP[w][quad * 4 + r][nb * 16 + fr] = __float2bfloat16(p[nb][r]);
            bfrag pa0 = *(const bfrag*)(&sP[w][fr][fq]);
            bfrag pa1 = *(const bfrag*)(&sP[w][fr][32 + fq]);
            __builtin_amdgcn_s_setprio(1);                     // T5: favor MFMA wave
            for (int nb = 0; nb < 4; ++nb) {
                const bf16* vr = sVp + (nb * 16 + fr) * 64;
                bfrag vb0 = *(const bfrag*)(vr + c0);
                bfrag vb1 = *(const bfrag*)(vr + (c0 ^ 32));
                o[nb] = __builtin_amdgcn_mfma_f32_16x16x32_bf16(pa0, vb0, o[nb], 0, 0, 0);
                o[nb] = __builtin_amdgcn_mfma_f32_16x16x32_bf16(pa1, vb1, o[nb], 0, 0, 0);
            }
            __builtin_amdgcn_s_setprio(0);
        };

        for (int kt = 0; kt <= qt; kt += 2) {
            const int k0 = kt * 64;
            const bool two = (kt + 1 <= qt);
            gload_lds16(Kbh + (size_t)(k0 + srow) * HD_ + sgc,      sK[0] + t * 8);
            gload_lds16(Kbh + (size_t)(k0 + 32 + srow) * HD_ + sgc, sK[0] + 2048 + t * 8);
            gload_lds16(Vbh + (size_t)srow * T_ + k0 + sgc,         sVt[0] + t * 8);
            gload_lds16(Vbh + (size_t)(srow + 32) * T_ + k0 + sgc,  sVt[0] + 2048 + t * 8);
            if (two) {
                const int k1 = k0 + 64;
                gload_lds16(Kbh + (size_t)(k1 + srow) * HD_ + sgc,      sK[1] + t * 8);
                gload_lds16(Kbh + (size_t)(k1 + 32 + srow) * HD_ + sgc, sK[1] + 2048 + t * 8);
                gload_lds16(Vbh + (size_t)srow * T_ + k1 + sgc,         sVt[1] + t * 8);
                gload_lds16(Vbh + (size_t)(srow + 32) * T_ + k1 + sgc,  sVt[1] + 2048 + t * 8);
            }
            __syncthreads();
            tile_step(kt, sK[0], sVt[0]);
            if (two) tile_step(kt + 1, sK[1], sVt[1]);
            __syncthreads();
        }

        for (int r = 0; r < 4; ++r) {
            float l = rowl[r];
            l += __shfl_xor(l, 1);
            l += __shfl_xor(l, 2);
            l += __shfl_xor(l, 4);
            l += __shfl_xor(l, 8);
            const float inv = 1.0f / l;
            const int tt = q0 + w * 16 + quad * 4 + r;
            bf16* yrow = Y + ((size_t)b_ * T_ + tt) * C_ + h_ * HD_;
            for (int nb = 0; nb < 4; ++nb)
                yrow[nb * 16 + fr] = __float2bfloat16(o[nb][r] * inv);
        }
    }
}

extern "C" void kernel_launch(void* const* d_in, const int* in_sizes, int n_in,
                              void* d_out, int out_size, void* d_ws, size_t ws_size,
                              hipStream_t stream) {
    const float* x      = (const float*)d_in[0];
    const float* W_attn = (const float*)d_in[1];
    const float* b_attn = (const float*)d_in[2];
    const float* W_proj = (const float*)d_in[3];
    const float* b_proj = (const float*)d_in[4];
    float* out = (float*)d_out;

    const size_t per = (size_t)B_ * H_ * T_ * HD_;   // 6291456 bf16
    bf16* Q   = (bf16*)d_ws;
    bf16* K   = Q + per;
    bf16* Vt  = K + per;                 // transposed V [B,H,64,T]
    bf16* XbY = Vt + per;                // x-bf16, later attention output Y
    bf16* WaT = XbY + per;
    bf16* WpT = WaT + (size_t)N3_ * C_;

    static bool s_attr = false;
    if (!s_attr) {
        hipFuncSetAttribute((const void*)qkv_p_kernel,
                            hipFuncAttributeMaxDynamicSharedMemorySize, 81920);
        hipFuncSetAttribute((const void*)proj_p_kernel,
                            hipFuncAttributeMaxDynamicSharedMemorySize, 57344);
        s_attr = true;
    }

    cvt_all_kernel<<<dim3(XBLK + WABLK + 576), dim3(256), 0, stream>>>(
        x, XbY, W_attn, WaT, W_proj, WpT);
    qkv_p_kernel<<<dim3(768), dim3(256), 81920, stream>>>(
        XbY, WaT, b_attn, Q, K, Vt);
    flash_attn_kernel<<<dim3(768), dim3(256), 0, stream>>>(Q, K, Vt, XbY);
    proj_p_kernel<<<dim3(512), dim3(256), 57344, stream>>>(
        XbY, WpT, b_proj, out);
}